// Round 1
// 486.463 us; speedup vs baseline: 1.0545x; 1.0545x over previous
//
#include <hip/hip_runtime.h>
#include <hip/hip_bf16.h>

// GCN forward on MI355X.
// Pipeline: prep(cvt x->bf16 | bucket count | pack W1,W2) -> bucket scan -> LDS binning (4B words)
//           -> per-bucket reorder (emits 4B packed edges) -> FUSED [SpMM1 gather -> LDS tile ->
//           MFMA GEMM1+ReLU -> MFMA proj(8)] -> fused SpMM2+bias+log_softmax.
// Algebra: spmm(A,h2)@W2 == spmm(A, h2@W2); h1 and h2 never hit global memory.
// Staged word (bcv): bits[16:0]=col, bits[24:17]=row&255, bits[31:25]=val q7 (val~q/128).
// Edge word: bits[16:0]=col, bits[31:17]=top-15 fp32 bits of q/128 (exact, e8m6).
// R1: Phase-A gather rewritten scalar-broadcast: v_readlane -> SGPR decode -> SGPR-base
//     global_load_dwordx2, groups of 8 edges (8 loads in flight/wave, no bpermute chain).

constexpr int N_NODES = 100000;
constexpr int N_EDGES = 3200000;
constexpr int D = 256;
constexpr int NCLS = 8;

constexpr int NBUCK  = 391;    // bucket = row >> 8 (256 rows/bucket)
constexpr int BCHUNK = 6400;   // edges per binning block; 500 * 6400 == N_EDGES
constexpr int EPT    = BCHUNK / 256;

constexpr int CVT_BLOCKS  = (N_NODES * D / 4) / 256;   // 25000
constexpr int CNT_BLOCKS  = N_EDGES / BCHUNK;          // 500
constexpr int PACK_BLOCKS = D * D / 256;               // 256 (W1) ; +1 block for W2

typedef __attribute__((ext_vector_type(8))) short bf16x8;
typedef __attribute__((ext_vector_type(4))) float f32x4;

__device__ inline unsigned short f2bf(float f) {
    __hip_bfloat16 h = __float2bfloat16(f);   // RNE
    return __builtin_bit_cast(unsigned short, h);
}
__device__ inline float bflo(unsigned u) { return __uint_as_float(u << 16); }
__device__ inline float bfhi(unsigned u) { return __uint_as_float(u & 0xffff0000u); }

// ---------------- prep: cvt | bin_count | w1_pack | w2_pack (one dispatch) ----------------

__global__ __launch_bounds__(256) void prep_kernel(const float* __restrict__ x,
                                                   unsigned short* __restrict__ xbf,
                                                   const int* __restrict__ row,
                                                   int* __restrict__ bucket_cnt,
                                                   const float* __restrict__ W1,
                                                   unsigned short* __restrict__ w1p,
                                                   const float* __restrict__ W2,
                                                   unsigned short* __restrict__ w2p) {
    const int bid = blockIdx.x;
    if (bid < CVT_BLOCKS) {
        int i = bid * 256 + threadIdx.x;
        float4 v = ((const float4*)x)[i];
        ushort4 o;
        o.x = f2bf(v.x); o.y = f2bf(v.y); o.z = f2bf(v.z); o.w = f2bf(v.w);
        ((ushort4*)xbf)[i] = o;
    } else if (bid < CVT_BLOCKS + CNT_BLOCKS) {
        __shared__ int h[NBUCK];
        for (int i = threadIdx.x; i < NBUCK; i += 256) h[i] = 0;
        __syncthreads();
        const int base = (bid - CVT_BLOCKS) * BCHUNK + threadIdx.x;
        #pragma unroll
        for (int j = 0; j < EPT; j++) atomicAdd(&h[row[base + j * 256] >> 8], 1);
        __syncthreads();
        for (int i = threadIdx.x; i < NBUCK; i += 256)
            if (h[i]) atomicAdd(&bucket_cnt[i], h[i]);
    } else if (bid < CVT_BLOCKS + CNT_BLOCKS + PACK_BLOCKS) {
        int idx = (bid - CVT_BLOCKS - CNT_BLOCKS) * 256 + threadIdx.x;
        int j = idx & 7, lane = (idx >> 3) & 63, s = (idx >> 9) & 7, nt = idx >> 12;
        int k = s * 32 + (lane >> 4) * 8 + j;
        int n = nt * 16 + (lane & 15);
        w1p[idx] = f2bf(W1[k * D + n]);
    } else {
        // W2 B-frag pack: 8 k-steps x 64 lanes x 8 j (n>=8 zero-padded)
        for (int i = threadIdx.x; i < 8 * 64 * 8; i += 256) {
            int j = i & 7, lane = (i >> 3) & 63, s = i >> 9;
            int k = s * 32 + ((lane >> 4)) * 8 + j;
            int n = lane & 15;
            w2p[i] = (n < NCLS) ? f2bf(W2[k * NCLS + n]) : (unsigned short)0;
        }
    }
}

// ---------------- CSR build: bucket scan (1 block) ----------------

__global__ __launch_bounds__(256) void bucket_scan_kernel(const int* __restrict__ bucket_cnt,
                                                          int* __restrict__ bucket_base,
                                                          int* __restrict__ bucket_next) {
    __shared__ int h[512];
    const int t = threadIdx.x;
    int c0 = (t < NBUCK) ? bucket_cnt[t] : 0;
    int c1 = (t + 256 < NBUCK) ? bucket_cnt[t + 256] : 0;
    h[t] = c0; h[t + 256] = c1;
    __syncthreads();
    for (int o = 1; o < 512; o <<= 1) {
        int v0 = (t >= o) ? h[t - o] : 0;
        int v1 = (t + 256 >= o) ? h[t + 256 - o] : 0;
        __syncthreads();
        h[t] += v0; h[t + 256] += v1;
        __syncthreads();
    }
    if (t < NBUCK)        { int e = h[t] - c0;        bucket_base[t] = e;        bucket_next[t] = e; }
    if (t + 256 < NBUCK)  { int e = h[t + 256] - c1;  bucket_base[t + 256] = e;  bucket_next[t + 256] = e; }
    if (t == 0) bucket_base[NBUCK] = h[511];
}

// ---------------- CSR build: LDS-staged binning (4B words), coalesced copy-out ----------------

__global__ __launch_bounds__(256) void bin_scatter_kernel(const int* __restrict__ row,
                                                          const int* __restrict__ col,
                                                          const float* __restrict__ val,
                                                          int* __restrict__ bucket_next,
                                                          int* __restrict__ bcv) {
    __shared__ int s_cv[BCHUNK];             // 25600 B
    __shared__ unsigned short s_bk[BCHUNK];  // 12800 B
    __shared__ int s_h[512];                 //  2048 B (hist -> inclusive scan)
    __shared__ int s_base[512];              //  2048 B (gbase[b] - excl[b])
    __shared__ int s_cur[NBUCK];             //  1564 B
    const int t = threadIdx.x;
    const int base = blockIdx.x * BCHUNK + t;

    int rl[EPT]; int cvl[EPT];
    #pragma unroll
    for (int j = 0; j < EPT; j++) {
        int i = base + j * 256;
        int r = row[i];
        rl[j] = r;
        // q7 = round(val*128) clamped to 127; val in [0,1)
        unsigned q = (unsigned)__builtin_fminf(val[i] * 128.f + 0.5f, 127.f);
        cvl[j] = col[i] | ((r & 255) << 17) | (int)(q << 25);
    }
    s_h[t] = 0; s_h[t + 256] = 0;
    __syncthreads();
    #pragma unroll
    for (int j = 0; j < EPT; j++) atomicAdd(&s_h[rl[j] >> 8], 1);
    __syncthreads();
    int c0 = s_h[t], c1 = s_h[t + 256];
    for (int o = 1; o < 512; o <<= 1) {
        int v0 = (t >= o) ? s_h[t - o] : 0;
        int v1 = (t + 256 >= o) ? s_h[t + 256 - o] : 0;
        __syncthreads();
        s_h[t] += v0; s_h[t + 256] += v1;
        __syncthreads();
    }
    const int e0 = s_h[t] - c0;
    const int e1 = s_h[t + 256] - c1;
    if (t < NBUCK) s_cur[t] = e0;
    if (t + 256 < NBUCK) s_cur[t + 256] = e1;
    __syncthreads();
    #pragma unroll
    for (int j = 0; j < EPT; j++) {
        int b = rl[j] >> 8;
        int q = atomicAdd(&s_cur[b], 1);
        s_cv[q] = cvl[j];
        s_bk[q] = (unsigned short)b;
    }
    if (t < NBUCK)       s_base[t]       = (c0 > 0 ? atomicAdd(&bucket_next[t], c0)       : 0) - e0;
    if (t + 256 < NBUCK) s_base[t + 256] = (c1 > 0 ? atomicAdd(&bucket_next[t + 256], c1) : 0) - e1;
    __syncthreads();
    for (int i = t; i < BCHUNK; i += 256) {
        bcv[s_base[s_bk[i]] + i] = s_cv[i];
    }
}

// ---------------- CSR build: per-bucket reorder (+ row offsets, 4B packed edges) ----------------
// Converts q7 -> exact e8m6 float top-15 bits so SpMM decode is a single AND.

__global__ __launch_bounds__(1024) void reorder_kernel(const int* __restrict__ bucket_base,
                                                       const int* __restrict__ bcv,
                                                       int* __restrict__ offsets,
                                                       int* __restrict__ edges) {
    __shared__ int rh[256];
    __shared__ int cur[256];
    const int b = blockIdx.x;
    const int t = threadIdx.x;
    const int base = bucket_base[b];
    const int cnt  = bucket_base[b + 1] - base;

    if (t < 256) rh[t] = 0;
    __syncthreads();
    for (int i = t; i < cnt; i += 1024) atomicAdd(&rh[((unsigned)bcv[base + i] >> 17) & 255], 1);
    __syncthreads();
    const int myc = (t < 256) ? rh[t] : 0;
    for (int o = 1; o < 256; o <<= 1) {
        int v = (t < 256 && t >= o) ? rh[t - o] : 0;
        __syncthreads();
        if (t < 256) rh[t] += v;
        __syncthreads();
    }
    if (t < 256) {
        const int excl = rh[t] - myc;
        const int grow = (b << 8) + t;
        if (grow <= N_NODES) offsets[grow] = base + excl;
        cur[t] = base + excl;
    }
    __syncthreads();
    for (int i = t; i < cnt; i += 1024) {
        const unsigned wrd = (unsigned)bcv[base + i];
        const int r8 = (wrd >> 17) & 255;
        const int p = atomicAdd(&cur[r8], 1);
        const float f = (float)(wrd >> 25) * 0.0078125f;   // q/128, <=6 mantissa bits -> exact
        edges[p] = (int)((__float_as_uint(f) & 0xFFFE0000u) | (wrd & 0x1FFFFu));
    }
}

// ---------------- FUSED: SpMM1 gather -> LDS tile -> MFMA GEMM1+ReLU -> MFMA proj ----------------
// 32 nodes/block (100000 = 3125*32 exact), 4 waves. Phase A: wave gathers 8 nodes
// (wave-per-node loop, lane l covers features [4l,4l+4)). Edge words are broadcast to
// SGPRs via v_readlane so decode is scalar and the gather load is SGPR-base + lane
// offset; 8 independent loads in flight per wave. Phase B: 32x256 MFMA GEMM from LDS
// tile + packed W1, bias+relu back into tile. Phase C: MFMA proj -> g.

constexpr int SCPITCH = 264;   // shorts; 528B rows, 16B-aligned

__global__ __launch_bounds__(256) void spmm_gemm_proj_kernel(const int* __restrict__ offs,
                                                             const int* __restrict__ edges,
                                                             const unsigned short* __restrict__ xbf,
                                                             const unsigned short* __restrict__ w1p,
                                                             const float* __restrict__ b1,
                                                             const unsigned short* __restrict__ w2p,
                                                             float* __restrict__ g) {
    __shared__ unsigned short sC[32 * SCPITCH];   // 16.5 KB

    const int tid  = threadIdx.x;
    const int wave = tid >> 6;
    const int lane = tid & 63;
    const int quad = lane >> 4;
    const int l15  = lane & 15;
    const int row0 = blockIdx.x * 32;

    // ---- Phase A: gather-SpMM, 8 nodes per wave (scalar-broadcast edges) ----
    // Prefetch the wave's 9 CSR offsets once; broadcast via readlane.
    int off_l = 0;
    if (lane < 9) off_l = offs[row0 + wave * 8 + lane];

    for (int idx = 0; idx < 8; idx++) {
        const int s = __builtin_amdgcn_readlane(off_l, idx);
        const int e = __builtin_amdgcn_readlane(off_l, idx + 1);
        float4 acc = make_float4(0.f, 0.f, 0.f, 0.f);

        for (int base = s; base < e; base += 64) {
            const int rem = e - base;
            int ed = 0;                                // col 0, val +0.0 -> contributes 0
            if (lane < rem) ed = edges[base + lane];
            const int cnt = rem < 64 ? rem : 64;
            // groups of 8; tail group is zero-padded via ed==0 lanes (adds exactly 0)
            for (int gb = 0; gb < cnt; gb += 8) {
                unsigned wv[8]; uint2 p[8];
                #pragma unroll
                for (int u = 0; u < 8; u++)
                    wv[u] = (unsigned)__builtin_amdgcn_readlane(ed, gb + u);
                #pragma unroll
                for (int u = 0; u < 8; u++) {
                    const size_t c = wv[u] & 0x1FFFFu;     // uniform -> SGPR base
                    p[u] = *((const uint2*)(xbf + c * D) + lane);
                }
                #pragma unroll
                for (int u = 0; u < 8; u++) {
                    const float v = __uint_as_float(wv[u] & 0xFFFE0000u);
                    acc.x = fmaf(v, bflo(p[u].x), acc.x);
                    acc.y = fmaf(v, bfhi(p[u].x), acc.y);
                    acc.z = fmaf(v, bflo(p[u].y), acc.z);
                    acc.w = fmaf(v, bfhi(p[u].y), acc.w);
                }
            }
        }
        const int rl = wave * 8 + idx;
        ushort4 o;
        o.x = f2bf(acc.x); o.y = f2bf(acc.y); o.z = f2bf(acc.z); o.w = f2bf(acc.w);
        *(ushort4*)&sC[rl * SCPITCH + lane * 4] = o;
    }
    __syncthreads();

    // ---- Phase B: MFMA GEMM (32 x 256) ----
    const int ntb = wave * 4;
    f32x4 acc[2][4] = {};   // [mt][nt]

    #pragma unroll
    for (int s = 0; s < 8; s++) {
        bf16x8 a[2], b[4];
        #pragma unroll
        for (int mt = 0; mt < 2; mt++)
            a[mt] = __builtin_bit_cast(bf16x8,
                *(const uint4*)&sC[(mt * 16 + l15) * SCPITCH + s * 32 + quad * 8]);
        #pragma unroll
        for (int nt = 0; nt < 4; nt++)
            b[nt] = __builtin_bit_cast(bf16x8,
                *(const uint4*)(w1p + (((size_t)(ntb + nt) * 8 + s) * 64 + lane) * 8));
        #pragma unroll
        for (int mt = 0; mt < 2; mt++)
            #pragma unroll
            for (int nt = 0; nt < 4; nt++)
                acc[mt][nt] = __builtin_amdgcn_mfma_f32_16x16x32_bf16(a[mt], b[nt], acc[mt][nt], 0, 0, 0);
    }
    __syncthreads();   // all tile reads done before overwrite

    // bias + relu -> back into sC
    #pragma unroll
    for (int nt = 0; nt < 4; nt++) {
        const int n = (ntb + nt) * 16 + l15;
        const float bias = b1[n];
        #pragma unroll
        for (int mt = 0; mt < 2; mt++) {
            #pragma unroll
            for (int i = 0; i < 4; i++) {
                const int rl = mt * 16 + quad * 4 + i;
                float v = acc[mt][nt][i] + bias;
                sC[rl * SCPITCH + n] = f2bf(v > 0.f ? v : 0.f);
            }
        }
    }
    __syncthreads();

    // ---- Phase C: proj via MFMA (waves 0,1 cover the 2 row-tiles) ----
    if (wave < 2) {
        f32x4 pacc = {};
        #pragma unroll
        for (int s = 0; s < 8; s++) {
            bf16x8 a = __builtin_bit_cast(bf16x8,
                *(const uint4*)&sC[(wave * 16 + l15) * SCPITCH + s * 32 + quad * 8]);
            bf16x8 b = __builtin_bit_cast(bf16x8,
                *(const uint4*)(w2p + ((size_t)s * 64 + lane) * 8));
            pacc = __builtin_amdgcn_mfma_f32_16x16x32_bf16(a, b, pacc, 0, 0, 0);
        }
        if (l15 < NCLS) {
            #pragma unroll
            for (int i = 0; i < 4; i++) {
                const int grow = row0 + wave * 16 + quad * 4 + i;
                g[(size_t)grow * NCLS + l15] = pacc[i];
            }
        }
    }
}

// ---------------- fused SpMM2 (8-wide) + bias + log_softmax, half-wave per node ----------------

__global__ __launch_bounds__(256) void head_spmm_kernel(const int* __restrict__ offs,
                                                        const int* __restrict__ edges,
                                                        const float* __restrict__ g,
                                                        const float* __restrict__ b2,
                                                        float* __restrict__ out) {
    const int tid  = threadIdx.x;
    const int hw   = tid >> 5;
    const int hl   = tid & 31;
    const int node = blockIdx.x * 8 + hw;
    if (node >= N_NODES) return;

    const int s = offs[node];
    const int e = offs[node + 1];

    float acc[NCLS] = {};
    for (int base = s; base < e; base += 32) {
        const int rem = e - base;
        if (hl < rem) {
            const unsigned w = (unsigned)edges[base + hl];
            const int   c = (int)(w & 0x1FFFFu);
            const float v = __uint_as_float(w & 0xFFFE0000u);
            const float4* gp = (const float4*)(g + (size_t)c * NCLS);
            const float4 lo = gp[0];
            const float4 hi = gp[1];
            acc[0] = fmaf(v, lo.x, acc[0]); acc[1] = fmaf(v, lo.y, acc[1]);
            acc[2] = fmaf(v, lo.z, acc[2]); acc[3] = fmaf(v, lo.w, acc[3]);
            acc[4] = fmaf(v, hi.x, acc[4]); acc[5] = fmaf(v, hi.y, acc[5]);
            acc[6] = fmaf(v, hi.z, acc[6]); acc[7] = fmaf(v, hi.w, acc[7]);
        }
    }
    #pragma unroll
    for (int c = 0; c < NCLS; c++) {
        #pragma unroll
        for (int o = 16; o > 0; o >>= 1) acc[c] += __shfl_xor(acc[c], o);
    }

    float logits[NCLS];
    #pragma unroll
    for (int c = 0; c < NCLS; c++) logits[c] = acc[c] + b2[c];
    float m = logits[0];
    #pragma unroll
    for (int c = 1; c < NCLS; c++) m = fmaxf(m, logits[c]);
    float sum = 0.f;
    #pragma unroll
    for (int c = 0; c < NCLS; c++) sum += __expf(logits[c] - m);
    const float lse = m + __logf(sum);
    if (hl < NCLS) out[(size_t)node * NCLS + hl] = logits[hl] - lse;
}

// ---------------- launcher ----------------

extern "C" void kernel_launch(void* const* d_in, const int* in_sizes, int n_in,
                              void* d_out, int out_size, void* d_ws, size_t ws_size,
                              hipStream_t stream) {
    const float* x       = (const float*)d_in[0];
    const int*   adj_row = (const int*)  d_in[1];
    const int*   adj_col = (const int*)  d_in[2];
    const float* adj_val = (const float*)d_in[3];
    const float* W1      = (const float*)d_in[4];
    const float* b1      = (const float*)d_in[5];
    const float* W2      = (const float*)d_in[6];
    const float* b2      = (const float*)d_in[7];
    float* out = (float*)d_out;

    char* w = (char*)d_ws;
    auto alloc = [&](size_t bytes) -> char* {
        char* p = w;
        w += (bytes + 255) & ~(size_t)255;
        return p;
    };
    int*            bucket_cnt  = (int*)  alloc((NBUCK + 1) * 4);
    int*            bucket_base = (int*)  alloc((NBUCK + 1) * 4);
    int*            bucket_next = (int*)  alloc((NBUCK + 1) * 4);
    int*            offsets     = (int*)  alloc(((size_t)N_NODES + 1) * 4);
    int*            bcv         = (int*)  alloc((size_t)N_EDGES * 4);
    int*            edges       = (int*)  alloc((size_t)N_EDGES * 4);
    unsigned short* xbf         = (unsigned short*)alloc((size_t)N_NODES * D * 2);
    unsigned short* w1p         = (unsigned short*)alloc((size_t)D * D * 2);
    unsigned short* w2p         = (unsigned short*)alloc((size_t)8 * 64 * 8 * 2);
    float*          g           = (float*)alloc((size_t)N_NODES * NCLS * 4);

    hipMemsetAsync(bucket_cnt, 0, (NBUCK + 1) * 4, stream);

    prep_kernel<<<CVT_BLOCKS + CNT_BLOCKS + PACK_BLOCKS + 1, 256, 0, stream>>>(
        x, xbf, adj_row, bucket_cnt, W1, w1p, W2, w2p);

    bucket_scan_kernel<<<1, 256, 0, stream>>>(bucket_cnt, bucket_base, bucket_next);

    bin_scatter_kernel<<<N_EDGES / BCHUNK, 256, 0, stream>>>(
        adj_row, adj_col, adj_val, bucket_next, bcv);

    reorder_kernel<<<NBUCK, 1024, 0, stream>>>(bucket_base, bcv, offsets, edges);

    spmm_gemm_proj_kernel<<<N_NODES / 32, 256, 0, stream>>>(
        offsets, edges, xbf, w1p, b1, w2p, g);

    const int nb8 = (N_NODES + 7) / 8;
    head_spmm_kernel<<<nb8, 256, 0, stream>>>(offsets, edges, g, b2, out);
}

// Round 2
// 422.401 us; speedup vs baseline: 1.2144x; 1.1517x over previous
//
#include <hip/hip_runtime.h>
#include <hip/hip_bf16.h>

// GCN forward on MI355X.
// Pipeline: prep(quantize x->int8/row-scale | bucket count | pack W1,W2) -> bucket scan
//           -> LDS binning (4B words) -> per-bucket reorder (emits folded+raw 4B edges)
//           -> FUSED [SpMM1 int8 gather -> LDS tile -> MFMA GEMM1+ReLU -> MFMA proj(8)]
//           -> fused SpMM2+bias+log_softmax.
// Algebra: spmm(A,h2)@W2 == spmm(A, h2@W2); h1 and h2 never hit global memory.
// Staged word (bcv): bits[16:0]=col, bits[24:17]=row&255, bits[31:25]=val q7 (val~q/128).
// Edge word (edges, spmm1): bits[16:0]=col, bits[31:17]=top-15 fp32 bits of q/128*scl[col] (RNE).
// Edge word (edgr, spmm2): bits[16:0]=col, bits[31:17]=top-15 fp32 bits of q/128 (exact e8m6).
// R1: Phase-A gather scalar-broadcast: v_readlane -> SGPR decode -> SGPR-base loads, groups of 8.
// R2: x stored int8 with per-row scale (256B/row = 4 cache lines, was 8). Gather is
//     MSHR/line-rate capped (R1 post-mortem: ~85 lines/CU in flight), so halving lines/edge
//     ~doubles edge throughput. Scale folded into edge val at reorder (no lookup in hot loop).

constexpr int N_NODES = 100000;
constexpr int N_EDGES = 3200000;
constexpr int D = 256;
constexpr int NCLS = 8;

constexpr int NBUCK  = 391;    // bucket = row >> 8 (256 rows/bucket)
constexpr int BCHUNK = 6400;   // edges per binning block; 500 * 6400 == N_EDGES
constexpr int EPT    = BCHUNK / 256;

constexpr int CVT_BLOCKS  = N_NODES / 4;               // 25000 (4 rows/block, 1 row/wave)
constexpr int CNT_BLOCKS  = N_EDGES / BCHUNK;          // 500
constexpr int PACK_BLOCKS = D * D / 256;               // 256 (W1) ; +1 block for W2

typedef __attribute__((ext_vector_type(8))) short bf16x8;
typedef __attribute__((ext_vector_type(4))) float f32x4;

__device__ inline unsigned short f2bf(float f) {
    __hip_bfloat16 h = __float2bfloat16(f);   // RNE
    return __builtin_bit_cast(unsigned short, h);
}

// ---------------- prep: int8 quant | bin_count | w1_pack | w2_pack (one dispatch) ----------------

__global__ __launch_bounds__(256) void prep_kernel(const float* __restrict__ x,
                                                   unsigned char* __restrict__ x8,
                                                   float* __restrict__ scl,
                                                   const int* __restrict__ row,
                                                   int* __restrict__ bucket_cnt,
                                                   const float* __restrict__ W1,
                                                   unsigned short* __restrict__ w1p,
                                                   const float* __restrict__ W2,
                                                   unsigned short* __restrict__ w2p) {
    const int bid = blockIdx.x;
    if (bid < CVT_BLOCKS) {
        // one row per wave: lane l covers features [4l, 4l+4)
        const int wave = threadIdx.x >> 6;
        const int lane = threadIdx.x & 63;
        const int r = bid * 4 + wave;
        const float4 v = ((const float4*)x)[r * 64 + lane];
        float am = fmaxf(fmaxf(fabsf(v.x), fabsf(v.y)), fmaxf(fabsf(v.z), fabsf(v.w)));
        #pragma unroll
        for (int o = 32; o > 0; o >>= 1) am = fmaxf(am, __shfl_xor(am, o));
        const float inv = (am > 0.f) ? 127.f / am : 0.f;
        const int q0 = (int)rintf(v.x * inv);
        const int q1 = (int)rintf(v.y * inv);
        const int q2 = (int)rintf(v.z * inv);
        const int q3 = (int)rintf(v.w * inv);
        const unsigned pk = (unsigned)(q0 & 255) | ((unsigned)(q1 & 255) << 8) |
                            ((unsigned)(q2 & 255) << 16) | ((unsigned)(q3 & 255) << 24);
        ((unsigned*)x8)[r * 64 + lane] = pk;
        if (lane == 0) scl[r] = am * (1.f / 127.f);
    } else if (bid < CVT_BLOCKS + CNT_BLOCKS) {
        __shared__ int h[NBUCK];
        for (int i = threadIdx.x; i < NBUCK; i += 256) h[i] = 0;
        __syncthreads();
        const int base = (bid - CVT_BLOCKS) * BCHUNK + threadIdx.x;
        #pragma unroll
        for (int j = 0; j < EPT; j++) atomicAdd(&h[row[base + j * 256] >> 8], 1);
        __syncthreads();
        for (int i = threadIdx.x; i < NBUCK; i += 256)
            if (h[i]) atomicAdd(&bucket_cnt[i], h[i]);
    } else if (bid < CVT_BLOCKS + CNT_BLOCKS + PACK_BLOCKS) {
        int idx = (bid - CVT_BLOCKS - CNT_BLOCKS) * 256 + threadIdx.x;
        int j = idx & 7, lane = (idx >> 3) & 63, s = (idx >> 9) & 7, nt = idx >> 12;
        int k = s * 32 + (lane >> 4) * 8 + j;
        int n = nt * 16 + (lane & 15);
        w1p[idx] = f2bf(W1[k * D + n]);
    } else {
        // W2 B-frag pack: 8 k-steps x 64 lanes x 8 j (n>=8 zero-padded)
        for (int i = threadIdx.x; i < 8 * 64 * 8; i += 256) {
            int j = i & 7, lane = (i >> 3) & 63, s = i >> 9;
            int k = s * 32 + ((lane >> 4)) * 8 + j;
            int n = lane & 15;
            w2p[i] = (n < NCLS) ? f2bf(W2[k * NCLS + n]) : (unsigned short)0;
        }
    }
}

// ---------------- CSR build: bucket scan (1 block) ----------------

__global__ __launch_bounds__(256) void bucket_scan_kernel(const int* __restrict__ bucket_cnt,
                                                          int* __restrict__ bucket_base,
                                                          int* __restrict__ bucket_next) {
    __shared__ int h[512];
    const int t = threadIdx.x;
    int c0 = (t < NBUCK) ? bucket_cnt[t] : 0;
    int c1 = (t + 256 < NBUCK) ? bucket_cnt[t + 256] : 0;
    h[t] = c0; h[t + 256] = c1;
    __syncthreads();
    for (int o = 1; o < 512; o <<= 1) {
        int v0 = (t >= o) ? h[t - o] : 0;
        int v1 = (t + 256 >= o) ? h[t + 256 - o] : 0;
        __syncthreads();
        h[t] += v0; h[t + 256] += v1;
        __syncthreads();
    }
    if (t < NBUCK)        { int e = h[t] - c0;        bucket_base[t] = e;        bucket_next[t] = e; }
    if (t + 256 < NBUCK)  { int e = h[t + 256] - c1;  bucket_base[t + 256] = e;  bucket_next[t + 256] = e; }
    if (t == 0) bucket_base[NBUCK] = h[511];
}

// ---------------- CSR build: LDS-staged binning (4B words), coalesced copy-out ----------------

__global__ __launch_bounds__(256) void bin_scatter_kernel(const int* __restrict__ row,
                                                          const int* __restrict__ col,
                                                          const float* __restrict__ val,
                                                          int* __restrict__ bucket_next,
                                                          int* __restrict__ bcv) {
    __shared__ int s_cv[BCHUNK];             // 25600 B
    __shared__ unsigned short s_bk[BCHUNK];  // 12800 B
    __shared__ int s_h[512];                 //  2048 B (hist -> inclusive scan)
    __shared__ int s_base[512];              //  2048 B (gbase[b] - excl[b])
    __shared__ int s_cur[NBUCK];             //  1564 B
    const int t = threadIdx.x;
    const int base = blockIdx.x * BCHUNK + t;

    int rl[EPT]; int cvl[EPT];
    #pragma unroll
    for (int j = 0; j < EPT; j++) {
        int i = base + j * 256;
        int r = row[i];
        rl[j] = r;
        // q7 = round(val*128) clamped to 127; val in [0,1)
        unsigned q = (unsigned)__builtin_fminf(val[i] * 128.f + 0.5f, 127.f);
        cvl[j] = col[i] | ((r & 255) << 17) | (int)(q << 25);
    }
    s_h[t] = 0; s_h[t + 256] = 0;
    __syncthreads();
    #pragma unroll
    for (int j = 0; j < EPT; j++) atomicAdd(&s_h[rl[j] >> 8], 1);
    __syncthreads();
    int c0 = s_h[t], c1 = s_h[t + 256];
    for (int o = 1; o < 512; o <<= 1) {
        int v0 = (t >= o) ? s_h[t - o] : 0;
        int v1 = (t + 256 >= o) ? s_h[t + 256 - o] : 0;
        __syncthreads();
        s_h[t] += v0; s_h[t + 256] += v1;
        __syncthreads();
    }
    const int e0 = s_h[t] - c0;
    const int e1 = s_h[t + 256] - c1;
    if (t < NBUCK) s_cur[t] = e0;
    if (t + 256 < NBUCK) s_cur[t + 256] = e1;
    __syncthreads();
    #pragma unroll
    for (int j = 0; j < EPT; j++) {
        int b = rl[j] >> 8;
        int q = atomicAdd(&s_cur[b], 1);
        s_cv[q] = cvl[j];
        s_bk[q] = (unsigned short)b;
    }
    if (t < NBUCK)       s_base[t]       = (c0 > 0 ? atomicAdd(&bucket_next[t], c0)       : 0) - e0;
    if (t + 256 < NBUCK) s_base[t + 256] = (c1 > 0 ? atomicAdd(&bucket_next[t + 256], c1) : 0) - e1;
    __syncthreads();
    for (int i = t; i < BCHUNK; i += 256) {
        bcv[s_base[s_bk[i]] + i] = s_cv[i];
    }
}

// ---------------- CSR build: per-bucket reorder (+ row offsets, two 4B edge arrays) ----------------
// edges: val field = q/128 * scl[col], rounded to e8m6 (spmm1, int8-x compensated)
// edgr : val field = q/128 exact e8m6 (spmm2 over g)

__global__ __launch_bounds__(1024) void reorder_kernel(const int* __restrict__ bucket_base,
                                                       const int* __restrict__ bcv,
                                                       const float* __restrict__ scl,
                                                       int* __restrict__ offsets,
                                                       int* __restrict__ edges,
                                                       int* __restrict__ edgr) {
    __shared__ int rh[256];
    __shared__ int cur[256];
    const int b = blockIdx.x;
    const int t = threadIdx.x;
    const int base = bucket_base[b];
    const int cnt  = bucket_base[b + 1] - base;

    if (t < 256) rh[t] = 0;
    __syncthreads();
    for (int i = t; i < cnt; i += 1024) atomicAdd(&rh[((unsigned)bcv[base + i] >> 17) & 255], 1);
    __syncthreads();
    const int myc = (t < 256) ? rh[t] : 0;
    for (int o = 1; o < 256; o <<= 1) {
        int v = (t < 256 && t >= o) ? rh[t - o] : 0;
        __syncthreads();
        if (t < 256) rh[t] += v;
        __syncthreads();
    }
    if (t < 256) {
        const int excl = rh[t] - myc;
        const int grow = (b << 8) + t;
        if (grow <= N_NODES) offsets[grow] = base + excl;
        cur[t] = base + excl;
    }
    __syncthreads();
    for (int i = t; i < cnt; i += 1024) {
        const unsigned wrd = (unsigned)bcv[base + i];
        const int r8 = (wrd >> 17) & 255;
        const int c  = (int)(wrd & 0x1FFFFu);
        const int p = atomicAdd(&cur[r8], 1);
        const float f = (float)(wrd >> 25) * 0.0078125f;   // q/128, <=6 mantissa bits -> exact
        edgr[p] = (int)((__float_as_uint(f) & 0xFFFE0000u) | (unsigned)c);
        const float fs = f * scl[c];
        unsigned u = __float_as_uint(fs);
        u = (u + 0x00010000u) & 0xFFFE0000u;               // RNE-ish to e8m6
        edges[p] = (int)(u | (unsigned)c);
    }
}

// ---------------- FUSED: SpMM1 int8 gather -> LDS tile -> MFMA GEMM1+ReLU -> MFMA proj ----------------
// 32 nodes/block (100000 = 3125*32 exact), 4 waves. Phase A: wave gathers 8 nodes
// (wave-per-node loop, lane l covers features [4l,4l+4) = one dword of int8). Edge words
// broadcast to SGPRs via v_readlane; 8 independent dword loads (4 lines each) in flight.
// Phase B: 32x256 MFMA GEMM from LDS tile + packed W1, bias+relu back into tile.
// Phase C: MFMA proj -> g.

constexpr int SCPITCH = 264;   // shorts; 528B rows, 16B-aligned

__global__ __launch_bounds__(256) void spmm_gemm_proj_kernel(const int* __restrict__ offs,
                                                             const int* __restrict__ edges,
                                                             const unsigned char* __restrict__ x8,
                                                             const unsigned short* __restrict__ w1p,
                                                             const float* __restrict__ b1,
                                                             const unsigned short* __restrict__ w2p,
                                                             float* __restrict__ g) {
    __shared__ unsigned short sC[32 * SCPITCH];   // 16.5 KB

    const int tid  = threadIdx.x;
    const int wave = tid >> 6;
    const int lane = tid & 63;
    const int quad = lane >> 4;
    const int l15  = lane & 15;
    const int row0 = blockIdx.x * 32;

    // ---- Phase A: gather-SpMM, 8 nodes per wave (scalar-broadcast edges, int8 rows) ----
    int off_l = 0;
    if (lane < 9) off_l = offs[row0 + wave * 8 + lane];

    for (int idx = 0; idx < 8; idx++) {
        const int s = __builtin_amdgcn_readlane(off_l, idx);
        const int e = __builtin_amdgcn_readlane(off_l, idx + 1);
        float4 acc = make_float4(0.f, 0.f, 0.f, 0.f);

        for (int base = s; base < e; base += 64) {
            const int rem = e - base;
            int ed = 0;                                // col 0, val +0.0 -> contributes 0
            if (lane < rem) ed = edges[base + lane];
            const int cnt = rem < 64 ? rem : 64;
            // groups of 8; tail group zero-padded via ed==0 lanes (adds exactly 0)
            for (int gb = 0; gb < cnt; gb += 8) {
                unsigned wv[8]; unsigned p[8];
                #pragma unroll
                for (int u = 0; u < 8; u++)
                    wv[u] = (unsigned)__builtin_amdgcn_readlane(ed, gb + u);
                #pragma unroll
                for (int u = 0; u < 8; u++) {
                    const size_t c = wv[u] & 0x1FFFFu;     // uniform -> SGPR base
                    p[u] = *((const unsigned*)(x8 + (c << 8)) + lane);
                }
                #pragma unroll
                for (int u = 0; u < 8; u++) {
                    const float v = __uint_as_float(wv[u] & 0xFFFE0000u);
                    const unsigned pk = p[u];
                    acc.x = fmaf(v, (float)((int)(pk << 24) >> 24), acc.x);
                    acc.y = fmaf(v, (float)((int)(pk << 16) >> 24), acc.y);
                    acc.z = fmaf(v, (float)((int)(pk <<  8) >> 24), acc.z);
                    acc.w = fmaf(v, (float)((int)pk >> 24),         acc.w);
                }
            }
        }
        const int rl = wave * 8 + idx;
        ushort4 o;
        o.x = f2bf(acc.x); o.y = f2bf(acc.y); o.z = f2bf(acc.z); o.w = f2bf(acc.w);
        *(ushort4*)&sC[rl * SCPITCH + lane * 4] = o;
    }
    __syncthreads();

    // ---- Phase B: MFMA GEMM (32 x 256) ----
    const int ntb = wave * 4;
    f32x4 acc[2][4] = {};   // [mt][nt]

    #pragma unroll
    for (int s = 0; s < 8; s++) {
        bf16x8 a[2], b[4];
        #pragma unroll
        for (int mt = 0; mt < 2; mt++)
            a[mt] = __builtin_bit_cast(bf16x8,
                *(const uint4*)&sC[(mt * 16 + l15) * SCPITCH + s * 32 + quad * 8]);
        #pragma unroll
        for (int nt = 0; nt < 4; nt++)
            b[nt] = __builtin_bit_cast(bf16x8,
                *(const uint4*)(w1p + (((size_t)(ntb + nt) * 8 + s) * 64 + lane) * 8));
        #pragma unroll
        for (int mt = 0; mt < 2; mt++)
            #pragma unroll
            for (int nt = 0; nt < 4; nt++)
                acc[mt][nt] = __builtin_amdgcn_mfma_f32_16x16x32_bf16(a[mt], b[nt], acc[mt][nt], 0, 0, 0);
    }
    __syncthreads();   // all tile reads done before overwrite

    // bias + relu -> back into sC
    #pragma unroll
    for (int nt = 0; nt < 4; nt++) {
        const int n = (ntb + nt) * 16 + l15;
        const float bias = b1[n];
        #pragma unroll
        for (int mt = 0; mt < 2; mt++) {
            #pragma unroll
            for (int i = 0; i < 4; i++) {
                const int rl = mt * 16 + quad * 4 + i;
                float v = acc[mt][nt][i] + bias;
                sC[rl * SCPITCH + n] = f2bf(v > 0.f ? v : 0.f);
            }
        }
    }
    __syncthreads();

    // ---- Phase C: proj via MFMA (waves 0,1 cover the 2 row-tiles) ----
    if (wave < 2) {
        f32x4 pacc = {};
        #pragma unroll
        for (int s = 0; s < 8; s++) {
            bf16x8 a = __builtin_bit_cast(bf16x8,
                *(const uint4*)&sC[(wave * 16 + l15) * SCPITCH + s * 32 + quad * 8]);
            bf16x8 b = __builtin_bit_cast(bf16x8,
                *(const uint4*)(w2p + ((size_t)s * 64 + lane) * 8));
            pacc = __builtin_amdgcn_mfma_f32_16x16x32_bf16(a, b, pacc, 0, 0, 0);
        }
        if (l15 < NCLS) {
            #pragma unroll
            for (int i = 0; i < 4; i++) {
                const int grow = row0 + wave * 16 + quad * 4 + i;
                g[(size_t)grow * NCLS + l15] = pacc[i];
            }
        }
    }
}

// ---------------- fused SpMM2 (8-wide) + bias + log_softmax, half-wave per node ----------------

__global__ __launch_bounds__(256) void head_spmm_kernel(const int* __restrict__ offs,
                                                        const int* __restrict__ edgr,
                                                        const float* __restrict__ g,
                                                        const float* __restrict__ b2,
                                                        float* __restrict__ out) {
    const int tid  = threadIdx.x;
    const int hw   = tid >> 5;
    const int hl   = tid & 31;
    const int node = blockIdx.x * 8 + hw;
    if (node >= N_NODES) return;

    const int s = offs[node];
    const int e = offs[node + 1];

    float acc[NCLS] = {};
    for (int base = s; base < e; base += 32) {
        const int rem = e - base;
        if (hl < rem) {
            const unsigned w = (unsigned)edgr[base + hl];
            const int   c = (int)(w & 0x1FFFFu);
            const float v = __uint_as_float(w & 0xFFFE0000u);
            const float4* gp = (const float4*)(g + (size_t)c * NCLS);
            const float4 lo = gp[0];
            const float4 hi = gp[1];
            acc[0] = fmaf(v, lo.x, acc[0]); acc[1] = fmaf(v, lo.y, acc[1]);
            acc[2] = fmaf(v, lo.z, acc[2]); acc[3] = fmaf(v, lo.w, acc[3]);
            acc[4] = fmaf(v, hi.x, acc[4]); acc[5] = fmaf(v, hi.y, acc[5]);
            acc[6] = fmaf(v, hi.z, acc[6]); acc[7] = fmaf(v, hi.w, acc[7]);
        }
    }
    #pragma unroll
    for (int c = 0; c < NCLS; c++) {
        #pragma unroll
        for (int o = 16; o > 0; o >>= 1) acc[c] += __shfl_xor(acc[c], o);
    }

    float logits[NCLS];
    #pragma unroll
    for (int c = 0; c < NCLS; c++) logits[c] = acc[c] + b2[c];
    float m = logits[0];
    #pragma unroll
    for (int c = 1; c < NCLS; c++) m = fmaxf(m, logits[c]);
    float sum = 0.f;
    #pragma unroll
    for (int c = 0; c < NCLS; c++) sum += __expf(logits[c] - m);
    const float lse = m + __logf(sum);
    if (hl < NCLS) out[(size_t)node * NCLS + hl] = logits[hl] - lse;
}

// ---------------- launcher ----------------

extern "C" void kernel_launch(void* const* d_in, const int* in_sizes, int n_in,
                              void* d_out, int out_size, void* d_ws, size_t ws_size,
                              hipStream_t stream) {
    const float* x       = (const float*)d_in[0];
    const int*   adj_row = (const int*)  d_in[1];
    const int*   adj_col = (const int*)  d_in[2];
    const float* adj_val = (const float*)d_in[3];
    const float* W1      = (const float*)d_in[4];
    const float* b1      = (const float*)d_in[5];
    const float* W2      = (const float*)d_in[6];
    const float* b2      = (const float*)d_in[7];
    float* out = (float*)d_out;

    char* w = (char*)d_ws;
    auto alloc = [&](size_t bytes) -> char* {
        char* p = w;
        w += (bytes + 255) & ~(size_t)255;
        return p;
    };
    int*            bucket_cnt  = (int*)  alloc((NBUCK + 1) * 4);
    int*            bucket_base = (int*)  alloc((NBUCK + 1) * 4);
    int*            bucket_next = (int*)  alloc((NBUCK + 1) * 4);
    int*            offsets     = (int*)  alloc(((size_t)N_NODES + 1) * 4);
    int*            bcv         = (int*)  alloc((size_t)N_EDGES * 4);
    int*            edges       = (int*)  alloc((size_t)N_EDGES * 4);
    int*            edgr        = (int*)  alloc((size_t)N_EDGES * 4);
    unsigned char*  x8          = (unsigned char*)alloc((size_t)N_NODES * D);
    float*          scl         = (float*)alloc((size_t)N_NODES * 4);
    unsigned short* w1p         = (unsigned short*)alloc((size_t)D * D * 2);
    unsigned short* w2p         = (unsigned short*)alloc((size_t)8 * 64 * 8 * 2);
    float*          g           = (float*)alloc((size_t)N_NODES * NCLS * 4);

    hipMemsetAsync(bucket_cnt, 0, (NBUCK + 1) * 4, stream);

    prep_kernel<<<CVT_BLOCKS + CNT_BLOCKS + PACK_BLOCKS + 1, 256, 0, stream>>>(
        x, x8, scl, adj_row, bucket_cnt, W1, w1p, W2, w2p);

    bucket_scan_kernel<<<1, 256, 0, stream>>>(bucket_cnt, bucket_base, bucket_next);

    bin_scatter_kernel<<<N_EDGES / BCHUNK, 256, 0, stream>>>(
        adj_row, adj_col, adj_val, bucket_next, bcv);

    reorder_kernel<<<NBUCK, 1024, 0, stream>>>(bucket_base, bcv, scl, offsets, edges, edgr);

    spmm_gemm_proj_kernel<<<N_NODES / 32, 256, 0, stream>>>(
        offsets, edges, x8, w1p, b1, w2p, g);

    const int nb8 = (N_NODES + 7) / 8;
    head_spmm_kernel<<<nb8, 256, 0, stream>>>(offsets, edgr, g, b2, out);
}

// Round 3
// 404.300 us; speedup vs baseline: 1.2688x; 1.0448x over previous
//
#include <hip/hip_runtime.h>
#include <hip/hip_bf16.h>

// GCN forward on MI355X.
// Pipeline: prep(quantize x->int8/row-scale | bucket count | pack W1,W2) -> bucket scan
//           -> LDS binning (4B words) -> per-bucket reorder (emits ONE folded 4B edge array)
//           -> FUSED [SpMM1 int8 gather -> LDS tile -> MFMA GEMM1+ReLU -> MFMA proj -> g' bf16]
//           -> fused SpMM2+bias+log_softmax over g'.
// Algebra: spmm(A,h2)@W2 == spmm(A, h2@W2); h1 and h2 never hit global memory.
//          Head trick: edges hold a*scl_c (folded); Phase C stores g'_c = g_c/scl_c, so
//          head computes sum (a*scl_c)*(g_c/scl_c) = sum a*g_c exactly. ONE edge array.
// Staged word (bcv): bits[16:0]=col, bits[24:17]=row&255, bits[31:25]=val q7 (val~q/128).
// Edge word: bits[16:0]=col, bits[31:17]=top-15 fp32 bits of q/128*scl[col] (RNE, e8m6).
// R1: Phase-A gather scalar-broadcast: v_readlane -> SGPR decode -> SGPR-base loads, groups of 8.
// R2: x stored int8 with per-row scale (256B/row = 4 cache lines). Gather is MSHR/line-rate
//     capped (~0.16 lines/cyc/CU confirmed R1->R2), so halving lines/edge ~halved time.
// R3: single folded edge array (g' = g/scl trick) + g' stored bf16 16B/row so head does
//     1 gather load/edge (was 2) -> halves head's MSHR requests.

constexpr int N_NODES = 100000;
constexpr int N_EDGES = 3200000;
constexpr int D = 256;
constexpr int NCLS = 8;

constexpr int NBUCK  = 391;    // bucket = row >> 8 (256 rows/bucket)
constexpr int BCHUNK = 6400;   // edges per binning block; 500 * 6400 == N_EDGES
constexpr int EPT    = BCHUNK / 256;

constexpr int CVT_BLOCKS  = N_NODES / 4;               // 25000 (4 rows/block, 1 row/wave)
constexpr int CNT_BLOCKS  = N_EDGES / BCHUNK;          // 500
constexpr int PACK_BLOCKS = D * D / 256;               // 256 (W1) ; +1 block for W2

typedef __attribute__((ext_vector_type(8))) short bf16x8;
typedef __attribute__((ext_vector_type(4))) float f32x4;

__device__ inline unsigned short f2bf(float f) {
    __hip_bfloat16 h = __float2bfloat16(f);   // RNE
    return __builtin_bit_cast(unsigned short, h);
}
__device__ inline float bflo(unsigned u) { return __uint_as_float(u << 16); }
__device__ inline float bfhi(unsigned u) { return __uint_as_float(u & 0xffff0000u); }

// ---------------- prep: int8 quant | bin_count | w1_pack | w2_pack (one dispatch) ----------------

__global__ __launch_bounds__(256) void prep_kernel(const float* __restrict__ x,
                                                   unsigned char* __restrict__ x8,
                                                   float* __restrict__ scl,
                                                   const int* __restrict__ row,
                                                   int* __restrict__ bucket_cnt,
                                                   const float* __restrict__ W1,
                                                   unsigned short* __restrict__ w1p,
                                                   const float* __restrict__ W2,
                                                   unsigned short* __restrict__ w2p) {
    const int bid = blockIdx.x;
    if (bid < CVT_BLOCKS) {
        // one row per wave: lane l covers features [4l, 4l+4)
        const int wave = threadIdx.x >> 6;
        const int lane = threadIdx.x & 63;
        const int r = bid * 4 + wave;
        const float4 v = ((const float4*)x)[r * 64 + lane];
        float am = fmaxf(fmaxf(fabsf(v.x), fabsf(v.y)), fmaxf(fabsf(v.z), fabsf(v.w)));
        #pragma unroll
        for (int o = 32; o > 0; o >>= 1) am = fmaxf(am, __shfl_xor(am, o));
        am = fmaxf(am, 1e-5f);                 // keep scl finite/positive (g' = g/scl)
        const float inv = 127.f / am;
        const int q0 = (int)rintf(v.x * inv);
        const int q1 = (int)rintf(v.y * inv);
        const int q2 = (int)rintf(v.z * inv);
        const int q3 = (int)rintf(v.w * inv);
        const unsigned pk = (unsigned)(q0 & 255) | ((unsigned)(q1 & 255) << 8) |
                            ((unsigned)(q2 & 255) << 16) | ((unsigned)(q3 & 255) << 24);
        ((unsigned*)x8)[r * 64 + lane] = pk;
        if (lane == 0) scl[r] = am * (1.f / 127.f);
    } else if (bid < CVT_BLOCKS + CNT_BLOCKS) {
        __shared__ int h[NBUCK];
        for (int i = threadIdx.x; i < NBUCK; i += 256) h[i] = 0;
        __syncthreads();
        const int base = (bid - CVT_BLOCKS) * BCHUNK + threadIdx.x;
        #pragma unroll
        for (int j = 0; j < EPT; j++) atomicAdd(&h[row[base + j * 256] >> 8], 1);
        __syncthreads();
        for (int i = threadIdx.x; i < NBUCK; i += 256)
            if (h[i]) atomicAdd(&bucket_cnt[i], h[i]);
    } else if (bid < CVT_BLOCKS + CNT_BLOCKS + PACK_BLOCKS) {
        int idx = (bid - CVT_BLOCKS - CNT_BLOCKS) * 256 + threadIdx.x;
        int j = idx & 7, lane = (idx >> 3) & 63, s = (idx >> 9) & 7, nt = idx >> 12;
        int k = s * 32 + (lane >> 4) * 8 + j;
        int n = nt * 16 + (lane & 15);
        w1p[idx] = f2bf(W1[k * D + n]);
    } else {
        // W2 B-frag pack: 8 k-steps x 64 lanes x 8 j (n>=8 zero-padded)
        for (int i = threadIdx.x; i < 8 * 64 * 8; i += 256) {
            int j = i & 7, lane = (i >> 3) & 63, s = i >> 9;
            int k = s * 32 + ((lane >> 4)) * 8 + j;
            int n = lane & 15;
            w2p[i] = (n < NCLS) ? f2bf(W2[k * NCLS + n]) : (unsigned short)0;
        }
    }
}

// ---------------- CSR build: bucket scan (1 block) ----------------

__global__ __launch_bounds__(256) void bucket_scan_kernel(const int* __restrict__ bucket_cnt,
                                                          int* __restrict__ bucket_base,
                                                          int* __restrict__ bucket_next) {
    __shared__ int h[512];
    const int t = threadIdx.x;
    int c0 = (t < NBUCK) ? bucket_cnt[t] : 0;
    int c1 = (t + 256 < NBUCK) ? bucket_cnt[t + 256] : 0;
    h[t] = c0; h[t + 256] = c1;
    __syncthreads();
    for (int o = 1; o < 512; o <<= 1) {
        int v0 = (t >= o) ? h[t - o] : 0;
        int v1 = (t + 256 >= o) ? h[t + 256 - o] : 0;
        __syncthreads();
        h[t] += v0; h[t + 256] += v1;
        __syncthreads();
    }
    if (t < NBUCK)        { int e = h[t] - c0;        bucket_base[t] = e;        bucket_next[t] = e; }
    if (t + 256 < NBUCK)  { int e = h[t + 256] - c1;  bucket_base[t + 256] = e;  bucket_next[t + 256] = e; }
    if (t == 0) bucket_base[NBUCK] = h[511];
}

// ---------------- CSR build: LDS-staged binning (4B words), coalesced copy-out ----------------

__global__ __launch_bounds__(256) void bin_scatter_kernel(const int* __restrict__ row,
                                                          const int* __restrict__ col,
                                                          const float* __restrict__ val,
                                                          int* __restrict__ bucket_next,
                                                          int* __restrict__ bcv) {
    __shared__ int s_cv[BCHUNK];             // 25600 B
    __shared__ unsigned short s_bk[BCHUNK];  // 12800 B
    __shared__ int s_h[512];                 //  2048 B (hist -> inclusive scan)
    __shared__ int s_base[512];              //  2048 B (gbase[b] - excl[b])
    __shared__ int s_cur[NBUCK];             //  1564 B
    const int t = threadIdx.x;
    const int base = blockIdx.x * BCHUNK + t;

    int rl[EPT]; int cvl[EPT];
    #pragma unroll
    for (int j = 0; j < EPT; j++) {
        int i = base + j * 256;
        int r = row[i];
        rl[j] = r;
        // q7 = round(val*128) clamped to 127; val in [0,1)
        unsigned q = (unsigned)__builtin_fminf(val[i] * 128.f + 0.5f, 127.f);
        cvl[j] = col[i] | ((r & 255) << 17) | (int)(q << 25);
    }
    s_h[t] = 0; s_h[t + 256] = 0;
    __syncthreads();
    #pragma unroll
    for (int j = 0; j < EPT; j++) atomicAdd(&s_h[rl[j] >> 8], 1);
    __syncthreads();
    int c0 = s_h[t], c1 = s_h[t + 256];
    for (int o = 1; o < 512; o <<= 1) {
        int v0 = (t >= o) ? s_h[t - o] : 0;
        int v1 = (t + 256 >= o) ? s_h[t + 256 - o] : 0;
        __syncthreads();
        s_h[t] += v0; s_h[t + 256] += v1;
        __syncthreads();
    }
    const int e0 = s_h[t] - c0;
    const int e1 = s_h[t + 256] - c1;
    if (t < NBUCK) s_cur[t] = e0;
    if (t + 256 < NBUCK) s_cur[t + 256] = e1;
    __syncthreads();
    #pragma unroll
    for (int j = 0; j < EPT; j++) {
        int b = rl[j] >> 8;
        int q = atomicAdd(&s_cur[b], 1);
        s_cv[q] = cvl[j];
        s_bk[q] = (unsigned short)b;
    }
    if (t < NBUCK)       s_base[t]       = (c0 > 0 ? atomicAdd(&bucket_next[t], c0)       : 0) - e0;
    if (t + 256 < NBUCK) s_base[t + 256] = (c1 > 0 ? atomicAdd(&bucket_next[t + 256], c1) : 0) - e1;
    __syncthreads();
    for (int i = t; i < BCHUNK; i += 256) {
        bcv[s_base[s_bk[i]] + i] = s_cv[i];
    }
}

// ---------------- CSR build: per-bucket reorder (+ row offsets, ONE folded 4B edge array) ---------
// val field = q/128 * scl[col], rounded to e8m6. Head divides g by scl instead (exact algebra).

__global__ __launch_bounds__(1024) void reorder_kernel(const int* __restrict__ bucket_base,
                                                       const int* __restrict__ bcv,
                                                       const float* __restrict__ scl,
                                                       int* __restrict__ offsets,
                                                       int* __restrict__ edges) {
    __shared__ int rh[256];
    __shared__ int cur[256];
    const int b = blockIdx.x;
    const int t = threadIdx.x;
    const int base = bucket_base[b];
    const int cnt  = bucket_base[b + 1] - base;

    if (t < 256) rh[t] = 0;
    __syncthreads();
    for (int i = t; i < cnt; i += 1024) atomicAdd(&rh[((unsigned)bcv[base + i] >> 17) & 255], 1);
    __syncthreads();
    const int myc = (t < 256) ? rh[t] : 0;
    for (int o = 1; o < 256; o <<= 1) {
        int v = (t < 256 && t >= o) ? rh[t - o] : 0;
        __syncthreads();
        if (t < 256) rh[t] += v;
        __syncthreads();
    }
    if (t < 256) {
        const int excl = rh[t] - myc;
        const int grow = (b << 8) + t;
        if (grow <= N_NODES) offsets[grow] = base + excl;
        cur[t] = base + excl;
    }
    __syncthreads();
    for (int i = t; i < cnt; i += 1024) {
        const unsigned wrd = (unsigned)bcv[base + i];
        const int r8 = (wrd >> 17) & 255;
        const int c  = (int)(wrd & 0x1FFFFu);
        const int p = atomicAdd(&cur[r8], 1);
        const float f = (float)(wrd >> 25) * 0.0078125f;   // q/128, <=6 mantissa bits -> exact
        const float fs = f * scl[c];
        unsigned u = __float_as_uint(fs);
        u = (u + 0x00010000u) & 0xFFFE0000u;               // RNE-ish to e8m6
        edges[p] = (int)(u | (unsigned)c);
    }
}

// ---------------- FUSED: SpMM1 int8 gather -> LDS tile -> MFMA GEMM1+ReLU -> MFMA proj ----------------
// 32 nodes/block (100000 = 3125*32 exact), 4 waves. Phase A: wave gathers 8 nodes
// (wave-per-node loop, lane l covers features [4l,4l+4) = one dword of int8). Edge words
// broadcast to SGPRs via v_readlane; 8 independent dword loads (4 lines each) in flight.
// Phase B: 32x256 MFMA GEMM from LDS tile + packed W1, bias+relu back into tile.
// Phase C: MFMA proj -> g' = g/scl stored bf16 (16 B/row).

constexpr int SCPITCH = 264;   // shorts; 528B rows, 16B-aligned

__global__ __launch_bounds__(256) void spmm_gemm_proj_kernel(const int* __restrict__ offs,
                                                             const int* __restrict__ edges,
                                                             const unsigned char* __restrict__ x8,
                                                             const unsigned short* __restrict__ w1p,
                                                             const float* __restrict__ b1,
                                                             const unsigned short* __restrict__ w2p,
                                                             const float* __restrict__ scl,
                                                             unsigned short* __restrict__ g2) {
    __shared__ unsigned short sC[32 * SCPITCH];   // 16.5 KB

    const int tid  = threadIdx.x;
    const int wave = tid >> 6;
    const int lane = tid & 63;
    const int quad = lane >> 4;
    const int l15  = lane & 15;
    const int row0 = blockIdx.x * 32;

    // ---- Phase A: gather-SpMM, 8 nodes per wave (scalar-broadcast edges, int8 rows) ----
    int off_l = 0;
    if (lane < 9) off_l = offs[row0 + wave * 8 + lane];

    for (int idx = 0; idx < 8; idx++) {
        const int s = __builtin_amdgcn_readlane(off_l, idx);
        const int e = __builtin_amdgcn_readlane(off_l, idx + 1);
        float4 acc = make_float4(0.f, 0.f, 0.f, 0.f);

        for (int base = s; base < e; base += 64) {
            const int rem = e - base;
            int ed = 0;                                // col 0, val +0.0 -> contributes 0
            if (lane < rem) ed = edges[base + lane];
            const int cnt = rem < 64 ? rem : 64;
            // groups of 8; tail group zero-padded via ed==0 lanes (adds exactly 0)
            for (int gb = 0; gb < cnt; gb += 8) {
                unsigned wv[8]; unsigned p[8];
                #pragma unroll
                for (int u = 0; u < 8; u++)
                    wv[u] = (unsigned)__builtin_amdgcn_readlane(ed, gb + u);
                #pragma unroll
                for (int u = 0; u < 8; u++) {
                    const size_t c = wv[u] & 0x1FFFFu;     // uniform -> SGPR base
                    p[u] = *((const unsigned*)(x8 + (c << 8)) + lane);
                }
                #pragma unroll
                for (int u = 0; u < 8; u++) {
                    const float v = __uint_as_float(wv[u] & 0xFFFE0000u);
                    const unsigned pk = p[u];
                    acc.x = fmaf(v, (float)((int)(pk << 24) >> 24), acc.x);
                    acc.y = fmaf(v, (float)((int)(pk << 16) >> 24), acc.y);
                    acc.z = fmaf(v, (float)((int)(pk <<  8) >> 24), acc.z);
                    acc.w = fmaf(v, (float)((int)pk >> 24),         acc.w);
                }
            }
        }
        const int rl = wave * 8 + idx;
        ushort4 o;
        o.x = f2bf(acc.x); o.y = f2bf(acc.y); o.z = f2bf(acc.z); o.w = f2bf(acc.w);
        *(ushort4*)&sC[rl * SCPITCH + lane * 4] = o;
    }
    __syncthreads();

    // ---- Phase B: MFMA GEMM (32 x 256) ----
    const int ntb = wave * 4;
    f32x4 acc[2][4] = {};   // [mt][nt]

    #pragma unroll
    for (int s = 0; s < 8; s++) {
        bf16x8 a[2], b[4];
        #pragma unroll
        for (int mt = 0; mt < 2; mt++)
            a[mt] = __builtin_bit_cast(bf16x8,
                *(const uint4*)&sC[(mt * 16 + l15) * SCPITCH + s * 32 + quad * 8]);
        #pragma unroll
        for (int nt = 0; nt < 4; nt++)
            b[nt] = __builtin_bit_cast(bf16x8,
                *(const uint4*)(w1p + (((size_t)(ntb + nt) * 8 + s) * 64 + lane) * 8));
        #pragma unroll
        for (int mt = 0; mt < 2; mt++)
            #pragma unroll
            for (int nt = 0; nt < 4; nt++)
                acc[mt][nt] = __builtin_amdgcn_mfma_f32_16x16x32_bf16(a[mt], b[nt], acc[mt][nt], 0, 0, 0);
    }
    __syncthreads();   // all tile reads done before overwrite

    // bias + relu -> back into sC
    #pragma unroll
    for (int nt = 0; nt < 4; nt++) {
        const int n = (ntb + nt) * 16 + l15;
        const float bias = b1[n];
        #pragma unroll
        for (int mt = 0; mt < 2; mt++) {
            #pragma unroll
            for (int i = 0; i < 4; i++) {
                const int rl = mt * 16 + quad * 4 + i;
                float v = acc[mt][nt][i] + bias;
                sC[rl * SCPITCH + n] = f2bf(v > 0.f ? v : 0.f);
            }
        }
    }
    __syncthreads();

    // ---- Phase C: proj via MFMA (waves 0,1 cover the 2 row-tiles); store g' = g/scl as bf16 ----
    if (wave < 2) {
        f32x4 pacc = {};
        #pragma unroll
        for (int s = 0; s < 8; s++) {
            bf16x8 a = __builtin_bit_cast(bf16x8,
                *(const uint4*)&sC[(wave * 16 + l15) * SCPITCH + s * 32 + quad * 8]);
            bf16x8 b = __builtin_bit_cast(bf16x8,
                *(const uint4*)(w2p + ((size_t)s * 64 + lane) * 8));
            pacc = __builtin_amdgcn_mfma_f32_16x16x32_bf16(a, b, pacc, 0, 0, 0);
        }
        if (l15 < NCLS) {
            #pragma unroll
            for (int i = 0; i < 4; i++) {
                const int grow = row0 + wave * 16 + quad * 4 + i;
                const float sv = scl[grow];
                g2[(size_t)grow * NCLS + l15] = f2bf(pacc[i] / sv);
            }
        }
    }
}

// ---------------- fused SpMM2 (8-wide) + bias + log_softmax, half-wave per node ----------------
// Uses folded edges (a*scl_c) against g' = g/scl_c: one 16B load per edge.

__global__ __launch_bounds__(256) void head_spmm_kernel(const int* __restrict__ offs,
                                                        const int* __restrict__ edges,
                                                        const unsigned short* __restrict__ g2,
                                                        const float* __restrict__ b2,
                                                        float* __restrict__ out) {
    const int tid  = threadIdx.x;
    const int hw   = tid >> 5;
    const int hl   = tid & 31;
    const int node = blockIdx.x * 8 + hw;
    if (node >= N_NODES) return;

    const int s = offs[node];
    const int e = offs[node + 1];

    float acc[NCLS] = {};
    for (int base = s; base < e; base += 32) {
        const int rem = e - base;
        if (hl < rem) {
            const unsigned w = (unsigned)edges[base + hl];
            const int   c = (int)(w & 0x1FFFFu);
            const float v = __uint_as_float(w & 0xFFFE0000u);
            const uint4 q = *((const uint4*)g2 + c);   // 8 bf16 = 16 B
            acc[0] = fmaf(v, bflo(q.x), acc[0]); acc[1] = fmaf(v, bfhi(q.x), acc[1]);
            acc[2] = fmaf(v, bflo(q.y), acc[2]); acc[3] = fmaf(v, bfhi(q.y), acc[3]);
            acc[4] = fmaf(v, bflo(q.z), acc[4]); acc[5] = fmaf(v, bfhi(q.z), acc[5]);
            acc[6] = fmaf(v, bflo(q.w), acc[6]); acc[7] = fmaf(v, bfhi(q.w), acc[7]);
        }
    }
    #pragma unroll
    for (int c = 0; c < NCLS; c++) {
        #pragma unroll
        for (int o = 16; o > 0; o >>= 1) acc[c] += __shfl_xor(acc[c], o);
    }

    float logits[NCLS];
    #pragma unroll
    for (int c = 0; c < NCLS; c++) logits[c] = acc[c] + b2[c];
    float m = logits[0];
    #pragma unroll
    for (int c = 1; c < NCLS; c++) m = fmaxf(m, logits[c]);
    float sum = 0.f;
    #pragma unroll
    for (int c = 0; c < NCLS; c++) sum += __expf(logits[c] - m);
    const float lse = m + __logf(sum);
    if (hl < NCLS) out[(size_t)node * NCLS + hl] = logits[hl] - lse;
}

// ---------------- launcher ----------------

extern "C" void kernel_launch(void* const* d_in, const int* in_sizes, int n_in,
                              void* d_out, int out_size, void* d_ws, size_t ws_size,
                              hipStream_t stream) {
    const float* x       = (const float*)d_in[0];
    const int*   adj_row = (const int*)  d_in[1];
    const int*   adj_col = (const int*)  d_in[2];
    const float* adj_val = (const float*)d_in[3];
    const float* W1      = (const float*)d_in[4];
    const float* b1      = (const float*)d_in[5];
    const float* W2      = (const float*)d_in[6];
    const float* b2      = (const float*)d_in[7];
    float* out = (float*)d_out;

    char* w = (char*)d_ws;
    auto alloc = [&](size_t bytes) -> char* {
        char* p = w;
        w += (bytes + 255) & ~(size_t)255;
        return p;
    };
    int*            bucket_cnt  = (int*)  alloc((NBUCK + 1) * 4);
    int*            bucket_base = (int*)  alloc((NBUCK + 1) * 4);
    int*            bucket_next = (int*)  alloc((NBUCK + 1) * 4);
    int*            offsets     = (int*)  alloc(((size_t)N_NODES + 1) * 4);
    int*            bcv         = (int*)  alloc((size_t)N_EDGES * 4);
    int*            edges       = (int*)  alloc((size_t)N_EDGES * 4);
    unsigned char*  x8          = (unsigned char*)alloc((size_t)N_NODES * D);
    float*          scl         = (float*)alloc((size_t)N_NODES * 4);
    unsigned short* w1p         = (unsigned short*)alloc((size_t)D * D * 2);
    unsigned short* w2p         = (unsigned short*)alloc((size_t)8 * 64 * 8 * 2);
    unsigned short* g2          = (unsigned short*)alloc((size_t)N_NODES * NCLS * 2);

    hipMemsetAsync(bucket_cnt, 0, (NBUCK + 1) * 4, stream);

    prep_kernel<<<CVT_BLOCKS + CNT_BLOCKS + PACK_BLOCKS + 1, 256, 0, stream>>>(
        x, x8, scl, adj_row, bucket_cnt, W1, w1p, W2, w2p);

    bucket_scan_kernel<<<1, 256, 0, stream>>>(bucket_cnt, bucket_base, bucket_next);

    bin_scatter_kernel<<<N_EDGES / BCHUNK, 256, 0, stream>>>(
        adj_row, adj_col, adj_val, bucket_next, bcv);

    reorder_kernel<<<NBUCK, 1024, 0, stream>>>(bucket_base, bcv, scl, offsets, edges);

    spmm_gemm_proj_kernel<<<N_NODES / 32, 256, 0, stream>>>(
        offsets, edges, x8, w1p, b1, w2p, scl, g2);

    const int nb8 = (N_NODES + 7) / 8;
    head_spmm_kernel<<<nb8, 256, 0, stream>>>(offsets, edges, g2, b2, out);
}

// Round 5
// 384.354 us; speedup vs baseline: 1.3346x; 1.0519x over previous
//
#include <hip/hip_runtime.h>
#include <hip/hip_bf16.h>

// GCN forward on MI355X.
// Pipeline (5 kernels): prep(quantize x->int8/row-scale | pack W1,W2) -> bin_scatter (LDS binning
//   into padded buckets) -> per-bucket reorder (raw-val 4B edges + int2 row extents)
//   -> FUSED [SpMM1 int8 gather (scl via s_load) -> LDS tile -> MFMA GEMM1+ReLU -> MFMA proj -> g bf16]
//   -> fused SpMM2+bias+log_softmax over g.
// Algebra: spmm(A,h2)@W2 == spmm(A, h2@W2); h1 and h2 never hit global memory.
// Staged word (bcv): bits[16:0]=col, bits[24:17]=row&255, bits[31:25]=val q7 (val~q/128).
// Edge word: bits[16:0]=col, bits[31:17]=top-15 fp32 bits of q/128 (exact, e8m6).
// R1: Phase-A gather scalar-broadcast: v_readlane -> SGPR decode -> SGPR-base loads, groups of 8.
// R2: x stored int8 with per-row scale (256B/row = 4 cache lines). Gather is request/byte-rate
//     capped (~0.157 lines/cyc/CU, ~10B/cyc/CU through the CU<->L2 port).
// R3: head reads 16B bf16 g rows: 1 line-request per edge.
// R4: (a) scl[col] gather moved from reorder (vector requests) into spmm Phase A as uniform
//     s_load (scalar port) + 1 v_mul/edge; edges carry raw q7 vals, g stored raw bf16.
//     (b) count pass + scan kernel deleted: fixed-capacity padded buckets (CAP=8704 ~
//     8192+5.7sigma), scatter allocates via global atomicAdd; extents stored as int2.
// R4b: bin_scatter kept as its own kernel (merging into prep forced 44KB LDS on all 25k cvt
//     blocks -> occupancy loss on a memory-bound phase). R4 bench was an infra failure; resubmit.

constexpr int N_NODES = 100000;
constexpr int N_EDGES = 3200000;
constexpr int D = 256;
constexpr int NCLS = 8;

constexpr int NBUCK  = 391;    // bucket = row >> 8 (256 rows/bucket)
constexpr int BCAP   = 8704;   // padded bucket capacity (E[cnt]=8192, sigma~90)
constexpr int BCHUNK = 6400;   // edges per binning block; 500 * 6400 == N_EDGES
constexpr int EPT    = BCHUNK / 256;

constexpr int CVT_BLOCKS  = N_NODES / 4;               // 25000 (4 rows/block, 1 row/wave)
constexpr int PACK_BLOCKS = D * D / 256;               // 256 (W1) ; +1 block for W2

typedef __attribute__((ext_vector_type(8))) short bf16x8;
typedef __attribute__((ext_vector_type(4))) float f32x4;

__device__ inline unsigned short f2bf(float f) {
    __hip_bfloat16 h = __float2bfloat16(f);   // RNE
    return __builtin_bit_cast(unsigned short, h);
}
__device__ inline float bflo(unsigned u) { return __uint_as_float(u << 16); }
__device__ inline float bfhi(unsigned u) { return __uint_as_float(u & 0xffff0000u); }

// ---------------- prep: int8 quant | w1_pack | w2_pack ----------------

__global__ __launch_bounds__(256) void prep_kernel(const float* __restrict__ x,
                                                   unsigned char* __restrict__ x8,
                                                   float* __restrict__ scl,
                                                   const float* __restrict__ W1,
                                                   unsigned short* __restrict__ w1p,
                                                   const float* __restrict__ W2,
                                                   unsigned short* __restrict__ w2p) {
    const int bid = blockIdx.x;
    const int t = threadIdx.x;
    if (bid < CVT_BLOCKS) {
        // one row per wave: lane l covers features [4l, 4l+4)
        const int wave = t >> 6;
        const int lane = t & 63;
        const int r = bid * 4 + wave;
        const float4 v = ((const float4*)x)[r * 64 + lane];
        float am = fmaxf(fmaxf(fabsf(v.x), fabsf(v.y)), fmaxf(fabsf(v.z), fabsf(v.w)));
        #pragma unroll
        for (int o = 32; o > 0; o >>= 1) am = fmaxf(am, __shfl_xor(am, o));
        am = fmaxf(am, 1e-20f);
        const float inv = 127.f / am;
        const int q0 = (int)rintf(v.x * inv);
        const int q1 = (int)rintf(v.y * inv);
        const int q2 = (int)rintf(v.z * inv);
        const int q3 = (int)rintf(v.w * inv);
        const unsigned pk = (unsigned)(q0 & 255) | ((unsigned)(q1 & 255) << 8) |
                            ((unsigned)(q2 & 255) << 16) | ((unsigned)(q3 & 255) << 24);
        ((unsigned*)x8)[r * 64 + lane] = pk;
        if (lane == 0) scl[r] = am * (1.f / 127.f);
    } else if (bid < CVT_BLOCKS + PACK_BLOCKS) {
        int idx = (bid - CVT_BLOCKS) * 256 + t;
        int j = idx & 7, lane = (idx >> 3) & 63, s = (idx >> 9) & 7, nt = idx >> 12;
        int k = s * 32 + (lane >> 4) * 8 + j;
        int n = nt * 16 + (lane & 15);
        w1p[idx] = f2bf(W1[k * D + n]);
    } else {
        // W2 B-frag pack: 8 k-steps x 64 lanes x 8 j (n>=8 zero-padded)
        for (int i = t; i < 8 * 64 * 8; i += 256) {
            int j = i & 7, lane = (i >> 3) & 63, s = i >> 9;
            int k = s * 32 + ((lane >> 4)) * 8 + j;
            int n = lane & 15;
            w2p[i] = (n < NCLS) ? f2bf(W2[k * NCLS + n]) : (unsigned short)0;
        }
    }
}

// ---------------- binning: LDS-staged scatter into padded bucket regions ----------------

__global__ __launch_bounds__(256) void bin_scatter_kernel(const int* __restrict__ row,
                                                          const int* __restrict__ col,
                                                          const float* __restrict__ val,
                                                          int* __restrict__ bucket_fill,
                                                          int* __restrict__ bcv) {
    __shared__ int s_cv[BCHUNK];             // 25600 B
    __shared__ unsigned short s_bk[BCHUNK];  // 12800 B
    __shared__ int s_h[512];                 //  2048 B (hist -> inclusive scan)
    __shared__ int s_base[512];              //  2048 B (global base - excl)
    __shared__ int s_cur[NBUCK];             //  1564 B
    const int t = threadIdx.x;
    const int base = blockIdx.x * BCHUNK + t;

    int rl[EPT]; int cvl[EPT];
    #pragma unroll
    for (int j = 0; j < EPT; j++) {
        int i = base + j * 256;
        int r = row[i];
        rl[j] = r;
        // q7 = round(val*128) clamped to 127; val in [0,1)
        unsigned q = (unsigned)__builtin_fminf(val[i] * 128.f + 0.5f, 127.f);
        cvl[j] = col[i] | ((r & 255) << 17) | (int)(q << 25);
    }
    s_h[t] = 0; s_h[t + 256] = 0;
    __syncthreads();
    #pragma unroll
    for (int j = 0; j < EPT; j++) atomicAdd(&s_h[rl[j] >> 8], 1);
    __syncthreads();
    int c0 = s_h[t], c1 = s_h[t + 256];
    for (int o = 1; o < 512; o <<= 1) {
        int v0 = (t >= o) ? s_h[t - o] : 0;
        int v1 = (t + 256 >= o) ? s_h[t + 256 - o] : 0;
        __syncthreads();
        s_h[t] += v0; s_h[t + 256] += v1;
        __syncthreads();
    }
    const int e0 = s_h[t] - c0;
    const int e1 = s_h[t + 256] - c1;
    if (t < NBUCK) s_cur[t] = e0;
    if (t + 256 < NBUCK) s_cur[t + 256] = e1;
    __syncthreads();
    #pragma unroll
    for (int j = 0; j < EPT; j++) {
        int b = rl[j] >> 8;
        int q = atomicAdd(&s_cur[b], 1);
        s_cv[q] = cvl[j];
        s_bk[q] = (unsigned short)b;
    }
    if (t < NBUCK)
        s_base[t] = (c0 > 0 ? atomicAdd(&bucket_fill[t], c0) + t * BCAP : 0) - e0;
    if (t + 256 < NBUCK)
        s_base[t + 256] = (c1 > 0 ? atomicAdd(&bucket_fill[t + 256], c1) + (t + 256) * BCAP : 0) - e1;
    __syncthreads();
    for (int i = t; i < BCHUNK; i += 256) {
        bcv[s_base[s_bk[i]] + i] = s_cv[i];
    }
}

// ---------------- CSR build: per-bucket reorder (+ int2 row extents, raw-val 4B edges) ----------
// Converts q7 -> exact e8m6 float top-15 bits so SpMM decode is a single AND.

__global__ __launch_bounds__(1024) void reorder_kernel(const int* __restrict__ bucket_fill,
                                                       const int* __restrict__ bcv,
                                                       int2* __restrict__ offs2,
                                                       int* __restrict__ edges) {
    __shared__ int rh[256];
    __shared__ int cur[256];
    const int b = blockIdx.x;
    const int t = threadIdx.x;
    const int base = b * BCAP;
    const int cnt  = bucket_fill[b];

    if (t < 256) rh[t] = 0;
    __syncthreads();
    for (int i = t; i < cnt; i += 1024) atomicAdd(&rh[((unsigned)bcv[base + i] >> 17) & 255], 1);
    __syncthreads();
    const int myc = (t < 256) ? rh[t] : 0;
    for (int o = 1; o < 256; o <<= 1) {
        int v = (t < 256 && t >= o) ? rh[t - o] : 0;
        __syncthreads();
        if (t < 256) rh[t] += v;
        __syncthreads();
    }
    if (t < 256) {
        const int incl = rh[t];
        const int excl = incl - myc;
        const int grow = (b << 8) + t;
        if (grow < N_NODES) offs2[grow] = make_int2(base + excl, base + incl);
        cur[t] = base + excl;
    }
    __syncthreads();
    for (int i = t; i < cnt; i += 1024) {
        const unsigned wrd = (unsigned)bcv[base + i];
        const int r8 = (wrd >> 17) & 255;
        const int p = atomicAdd(&cur[r8], 1);
        const float f = (float)(wrd >> 25) * 0.0078125f;   // q/128, <=6 mantissa bits -> exact
        edges[p] = (int)((__float_as_uint(f) & 0xFFFE0000u) | (wrd & 0x1FFFFu));
    }
}

// ---------------- FUSED: SpMM1 int8 gather -> LDS tile -> MFMA GEMM1+ReLU -> MFMA proj ----------------
// 32 nodes/block (100000 = 3125*32 exact), 4 waves. Phase A: wave gathers 8 nodes
// (wave-per-node loop, lane l covers features [4l,4l+4) = one dword of int8). Edge words
// broadcast to SGPRs via v_readlane; per-edge scl[c] is a uniform (scalar-port) load folded
// with one v_mul. 8 independent dword loads (4 lines each) in flight per group.
// Phase B: 32x256 MFMA GEMM from LDS tile + packed W1, bias+relu back into tile.
// Phase C: MFMA proj -> raw g stored bf16 (16 B/row).

constexpr int SCPITCH = 264;   // shorts; 528B rows, 16B-aligned

__global__ __launch_bounds__(256) void spmm_gemm_proj_kernel(const int2* __restrict__ offs2,
                                                             const int* __restrict__ edges,
                                                             const unsigned char* __restrict__ x8,
                                                             const float* __restrict__ scl,
                                                             const unsigned short* __restrict__ w1p,
                                                             const float* __restrict__ b1,
                                                             const unsigned short* __restrict__ w2p,
                                                             unsigned short* __restrict__ g2) {
    __shared__ unsigned short sC[32 * SCPITCH];   // 16.5 KB

    const int tid  = threadIdx.x;
    const int wave = tid >> 6;
    const int lane = tid & 63;
    const int quad = lane >> 4;
    const int l15  = lane & 15;
    const int row0 = blockIdx.x * 32;

    // ---- Phase A: gather-SpMM, 8 nodes per wave (scalar-broadcast edges, int8 rows) ----
    int2 se = make_int2(0, 0);
    if (lane < 8) se = offs2[row0 + wave * 8 + lane];

    for (int idx = 0; idx < 8; idx++) {
        const int s = __builtin_amdgcn_readlane(se.x, idx);
        const int e = __builtin_amdgcn_readlane(se.y, idx);
        float4 acc = make_float4(0.f, 0.f, 0.f, 0.f);

        for (int base = s; base < e; base += 64) {
            const int rem = e - base;
            int ed = 0;                                // col 0, val +0.0 -> contributes 0
            if (lane < rem) ed = edges[base + lane];
            const int cnt = rem < 64 ? rem : 64;
            // groups of 8; tail group zero-padded via ed==0 lanes (adds exactly 0)
            for (int gb = 0; gb < cnt; gb += 8) {
                unsigned wv[8]; unsigned p[8]; float sv[8];
                #pragma unroll
                for (int u = 0; u < 8; u++)
                    wv[u] = (unsigned)__builtin_amdgcn_readlane(ed, gb + u);
                #pragma unroll
                for (int u = 0; u < 8; u++) {
                    const unsigned c = wv[u] & 0x1FFFFu;   // uniform -> SGPR
                    sv[u] = scl[c];                        // uniform -> s_load (scalar port)
                    p[u] = *((const unsigned*)(x8 + ((size_t)c << 8)) + lane);
                }
                #pragma unroll
                for (int u = 0; u < 8; u++) {
                    const float v = __uint_as_float(wv[u] & 0xFFFE0000u) * sv[u];
                    const unsigned pk = p[u];
                    acc.x = fmaf(v, (float)((int)(pk << 24) >> 24), acc.x);
                    acc.y = fmaf(v, (float)((int)(pk << 16) >> 24), acc.y);
                    acc.z = fmaf(v, (float)((int)(pk <<  8) >> 24), acc.z);
                    acc.w = fmaf(v, (float)((int)pk >> 24),         acc.w);
                }
            }
        }
        const int rl = wave * 8 + idx;
        ushort4 o;
        o.x = f2bf(acc.x); o.y = f2bf(acc.y); o.z = f2bf(acc.z); o.w = f2bf(acc.w);
        *(ushort4*)&sC[rl * SCPITCH + lane * 4] = o;
    }
    __syncthreads();

    // ---- Phase B: MFMA GEMM (32 x 256) ----
    const int ntb = wave * 4;
    f32x4 acc[2][4] = {};   // [mt][nt]

    #pragma unroll
    for (int s = 0; s < 8; s++) {
        bf16x8 a[2], b[4];
        #pragma unroll
        for (int mt = 0; mt < 2; mt++)
            a[mt] = __builtin_bit_cast(bf16x8,
                *(const uint4*)&sC[(mt * 16 + l15) * SCPITCH + s * 32 + quad * 8]);
        #pragma unroll
        for (int nt = 0; nt < 4; nt++)
            b[nt] = __builtin_bit_cast(bf16x8,
                *(const uint4*)(w1p + (((size_t)(ntb + nt) * 8 + s) * 64 + lane) * 8));
        #pragma unroll
        for (int mt = 0; mt < 2; mt++)
            #pragma unroll
            for (int nt = 0; nt < 4; nt++)
                acc[mt][nt] = __builtin_amdgcn_mfma_f32_16x16x32_bf16(a[mt], b[nt], acc[mt][nt], 0, 0, 0);
    }
    __syncthreads();   // all tile reads done before overwrite

    // bias + relu -> back into sC
    #pragma unroll
    for (int nt = 0; nt < 4; nt++) {
        const int n = (ntb + nt) * 16 + l15;
        const float bias = b1[n];
        #pragma unroll
        for (int mt = 0; mt < 2; mt++) {
            #pragma unroll
            for (int i = 0; i < 4; i++) {
                const int rl = mt * 16 + quad * 4 + i;
                float v = acc[mt][nt][i] + bias;
                sC[rl * SCPITCH + n] = f2bf(v > 0.f ? v : 0.f);
            }
        }
    }
    __syncthreads();

    // ---- Phase C: proj via MFMA (waves 0,1 cover the 2 row-tiles); store raw g as bf16 ----
    if (wave < 2) {
        f32x4 pacc = {};
        #pragma unroll
        for (int s = 0; s < 8; s++) {
            bf16x8 a = __builtin_bit_cast(bf16x8,
                *(const uint4*)&sC[(wave * 16 + l15) * SCPITCH + s * 32 + quad * 8]);
            bf16x8 b = __builtin_bit_cast(bf16x8,
                *(const uint4*)(w2p + ((size_t)s * 64 + lane) * 8));
            pacc = __builtin_amdgcn_mfma_f32_16x16x32_bf16(a, b, pacc, 0, 0, 0);
        }
        if (l15 < NCLS) {
            #pragma unroll
            for (int i = 0; i < 4; i++) {
                const int grow = row0 + wave * 16 + quad * 4 + i;
                g2[(size_t)grow * NCLS + l15] = f2bf(pacc[i]);
            }
        }
    }
}

// ---------------- fused SpMM2 (8-wide) + bias + log_softmax, half-wave per node ----------------
// Raw edges (q/128) against raw bf16 g rows: one 16B load per edge.

__global__ __launch_bounds__(256) void head_spmm_kernel(const int2* __restrict__ offs2,
                                                        const int* __restrict__ edges,
                                                        const unsigned short* __restrict__ g2,
                                                        const float* __restrict__ b2,
                                                        float* __restrict__ out) {
    const int tid  = threadIdx.x;
    const int hw   = tid >> 5;
    const int hl   = tid & 31;
    const int node = blockIdx.x * 8 + hw;
    if (node >= N_NODES) return;

    const int2 se = offs2[node];
    const int s = se.x;
    const int e = se.y;

    float acc[NCLS] = {};
    for (int base = s; base < e; base += 32) {
        const int rem = e - base;
        if (hl < rem) {
            const unsigned w = (unsigned)edges[base + hl];
            const int   c = (int)(w & 0x1FFFFu);
            const float v = __uint_as_float(w & 0xFFFE0000u);
            const uint4 q = *((const uint4*)g2 + c);   // 8 bf16 = 16 B
            acc[0] = fmaf(v, bflo(q.x), acc[0]); acc[1] = fmaf(v, bfhi(q.x), acc[1]);
            acc[2] = fmaf(v, bflo(q.y), acc[2]); acc[3] = fmaf(v, bfhi(q.y), acc[3]);
            acc[4] = fmaf(v, bflo(q.z), acc[4]); acc[5] = fmaf(v, bfhi(q.z), acc[5]);
            acc[6] = fmaf(v, bflo(q.w), acc[6]); acc[7] = fmaf(v, bfhi(q.w), acc[7]);
        }
    }
    #pragma unroll
    for (int c = 0; c < NCLS; c++) {
        #pragma unroll
        for (int o = 16; o > 0; o >>= 1) acc[c] += __shfl_xor(acc[c], o);
    }

    float logits[NCLS];
    #pragma unroll
    for (int c = 0; c < NCLS; c++) logits[c] = acc[c] + b2[c];
    float m = logits[0];
    #pragma unroll
    for (int c = 1; c < NCLS; c++) m = fmaxf(m, logits[c]);
    float sum = 0.f;
    #pragma unroll
    for (int c = 0; c < NCLS; c++) sum += __expf(logits[c] - m);
    const float lse = m + __logf(sum);
    if (hl < NCLS) out[(size_t)node * NCLS + hl] = logits[hl] - lse;
}

// ---------------- launcher ----------------

extern "C" void kernel_launch(void* const* d_in, const int* in_sizes, int n_in,
                              void* d_out, int out_size, void* d_ws, size_t ws_size,
                              hipStream_t stream) {
    const float* x       = (const float*)d_in[0];
    const int*   adj_row = (const int*)  d_in[1];
    const int*   adj_col = (const int*)  d_in[2];
    const float* adj_val = (const float*)d_in[3];
    const float* W1      = (const float*)d_in[4];
    const float* b1      = (const float*)d_in[5];
    const float* W2      = (const float*)d_in[6];
    const float* b2      = (const float*)d_in[7];
    float* out = (float*)d_out;

    char* w = (char*)d_ws;
    auto alloc = [&](size_t bytes) -> char* {
        char* p = w;
        w += (bytes + 255) & ~(size_t)255;
        return p;
    };
    int*            bucket_fill = (int*)  alloc((NBUCK + 1) * 4);
    int2*           offs2       = (int2*) alloc((size_t)N_NODES * 8);
    int*            bcv         = (int*)  alloc((size_t)NBUCK * BCAP * 4);
    int*            edges       = (int*)  alloc((size_t)NBUCK * BCAP * 4);
    unsigned char*  x8          = (unsigned char*)alloc((size_t)N_NODES * D);
    float*          scl         = (float*)alloc((size_t)N_NODES * 4);
    unsigned short* w1p         = (unsigned short*)alloc((size_t)D * D * 2);
    unsigned short* w2p         = (unsigned short*)alloc((size_t)8 * 64 * 8 * 2);
    unsigned short* g2          = (unsigned short*)alloc((size_t)N_NODES * NCLS * 2);

    hipMemsetAsync(bucket_fill, 0, (NBUCK + 1) * 4, stream);

    prep_kernel<<<CVT_BLOCKS + PACK_BLOCKS + 1, 256, 0, stream>>>(
        x, x8, scl, W1, w1p, W2, w2p);

    bin_scatter_kernel<<<N_EDGES / BCHUNK, 256, 0, stream>>>(
        adj_row, adj_col, adj_val, bucket_fill, bcv);

    reorder_kernel<<<NBUCK, 1024, 0, stream>>>(bucket_fill, bcv, offs2, edges);

    spmm_gemm_proj_kernel<<<N_NODES / 32, 256, 0, stream>>>(
        offs2, edges, x8, scl, w1p, b1, w2p, g2);

    const int nb8 = (N_NODES + 7) / 8;
    head_spmm_kernel<<<nb8, 256, 0, stream>>>(offs2, edges, g2, b2, out);
}